// Round 13
// baseline (206.013 us; speedup 1.0000x reference)
//
#include <hip/hip_runtime.h>
#include <hip/hip_bf16.h>

#define TOK_T 8
#define TOK_H 32
#define TOK_W 32
#define NTOK 8192
#define BATCH 2
#define DMODEL 256
#define D3 768
#define NHEADS 8
#define DHEAD 32

using short8  = __attribute__((ext_vector_type(8))) short;
using ushort8 = __attribute__((ext_vector_type(8))) unsigned short;
using f32x4   = __attribute__((ext_vector_type(4))) float;
using f32x2   = __attribute__((ext_vector_type(2))) float;

__device__ __forceinline__ ushort f2bf(float f) {
  __hip_bfloat16 h = __float2bfloat16(f);
  return *reinterpret_cast<ushort*>(&h);
}
__device__ __forceinline__ float bf2f(ushort u) {
  union { unsigned u; float f; } v; v.u = ((unsigned)u) << 16;
  return v.f;
}
__device__ __forceinline__ f32x2 bfpair(unsigned u) {
  union { unsigned u; float f; } lo, hi;
  lo.u = u << 16;
  hi.u = u & 0xffff0000u;
  f32x2 r; r[0] = lo.f; r[1] = hi.f;
  return r;
}

// ---------------- fused-convert GEMM (exact R12 kernel) ----------------
// 1D grid, XCD-colocating remap: xcd = bm&7, id = xcd + 8*((bm>>3)*NBN + bn).
template<int TBM, int TBN, int NW, int NBN, bool AF32, bool OUTBF16>
__global__ __launch_bounds__(NW * 64, 4) void gemm_fused(const void* __restrict__ Av,
                                                         const float* __restrict__ B,
                                                         void* __restrict__ Cv,
                                                         int ldc) {
  constexpr int NCW = TBN / 64;
  constexpr int NWR = NW / NCW;
  constexpr int MR  = TBM / (NWR * 16);
  constexpr int CHA = TBM * 4;
  constexpr int CHB = TBN * 4;
  constexpr int NT  = NW * 64;
  constexpr int CPT = (CHA + CHB) / NT;
  constexpr int SA  = CHA / NT;
  constexpr int ATILE = TBM * 32;
  constexpr int BTILE = TBN * 32;

  __shared__ __align__(16) ushort sm[2][ATILE + BTILE];

  const int tid  = threadIdx.x;
  const int lane = tid & 63;
  const int wid  = tid >> 6;
  const int wr   = wid / NCW;
  const int wc   = wid % NCW;
  const int bid  = blockIdx.x;
  const int xcd  = bid & 7;
  const int kk2  = bid >> 3;
  const int bm   = ((kk2 / NBN) * 8 + xcd) * TBM;
  const int bn   = (kk2 % NBN) * TBN;
  const int fr   = lane & 15;
  const int kb   = lane >> 4;

  float4  laf[SA > 0 ? SA : 1][2];
  ushort8 lab[SA > 0 ? SA : 1];
  float4  lbf[CPT - SA][2];

  auto load = [&](int kt) {
#pragma unroll
    for (int s = 0; s < SA; ++s) {
      int cc = tid + s * NT;
      int r = cc >> 2, sl = cc & 3;
      if constexpr (AF32) {
        const float* p = (const float*)Av + (size_t)(bm + r) * 256 + kt + sl * 8;
        laf[s][0] = *(const float4*)p;
        laf[s][1] = *(const float4*)(p + 4);
      } else {
        lab[s] = *(const ushort8*)((const ushort*)Av + (size_t)(bm + r) * 256 + kt + sl * 8);
      }
    }
#pragma unroll
    for (int s = 0; s < CPT - SA; ++s) {
      int cc = tid + (s + SA) * NT - CHA;
      int r = cc >> 2, sl = cc & 3;
      const float* p = B + (size_t)(bn + r) * 256 + kt + sl * 8;
      lbf[s][0] = *(const float4*)p;
      lbf[s][1] = *(const float4*)(p + 4);
    }
  };
  auto stow = [&](int buf) {
#pragma unroll
    for (int s = 0; s < SA; ++s) {
      int cc = tid + s * NT;
      int r = cc >> 2, sl = cc & 3;
      int sck = r * 4 + (sl ^ ((r >> 1) & 3));
      ushort8 v;
      if constexpr (AF32) {
        v[0] = f2bf(laf[s][0].x); v[1] = f2bf(laf[s][0].y);
        v[2] = f2bf(laf[s][0].z); v[3] = f2bf(laf[s][0].w);
        v[4] = f2bf(laf[s][1].x); v[5] = f2bf(laf[s][1].y);
        v[6] = f2bf(laf[s][1].z); v[7] = f2bf(laf[s][1].w);
      } else v = lab[s];
      *(ushort8*)&sm[buf][sck * 8] = v;
    }
#pragma unroll
    for (int s = 0; s < CPT - SA; ++s) {
      int cc = tid + (s + SA) * NT - CHA;
      int r = cc >> 2, sl = cc & 3;
      int sck = r * 4 + (sl ^ ((r >> 1) & 3));
      ushort8 v;
      v[0] = f2bf(lbf[s][0].x); v[1] = f2bf(lbf[s][0].y);
      v[2] = f2bf(lbf[s][0].z); v[3] = f2bf(lbf[s][0].w);
      v[4] = f2bf(lbf[s][1].x); v[5] = f2bf(lbf[s][1].y);
      v[6] = f2bf(lbf[s][1].z); v[7] = f2bf(lbf[s][1].w);
      *(ushort8*)&sm[buf][ATILE + sck * 8] = v;
    }
  };

  f32x4 acc[MR][4] = {};

  load(0);
  stow(0);
  __syncthreads();

  for (int it = 0; it < 8; ++it) {
    const int cur = it & 1;
    if (it < 7) load((it + 1) * 32);

    short8 af[MR], bf8[4];
#pragma unroll
    for (int m = 0; m < MR; ++m) {
      int r  = wr * (MR * 16) + m * 16 + fr;
      int ck = r * 4 + (kb ^ ((r >> 1) & 3));
      af[m] = *(const short8*)&sm[cur][ck * 8];
    }
#pragma unroll
    for (int n = 0; n < 4; ++n) {
      int r  = wc * 64 + n * 16 + fr;
      int ck = r * 4 + (kb ^ ((r >> 1) & 3));
      bf8[n] = *(const short8*)&sm[cur][ATILE + ck * 8];
    }
#pragma unroll
    for (int m = 0; m < MR; ++m)
#pragma unroll
      for (int n = 0; n < 4; ++n)
        acc[m][n] = __builtin_amdgcn_mfma_f32_16x16x32_bf16(af[m], bf8[n], acc[m][n], 0, 0, 0);

    if (it < 7) {
      stow(cur ^ 1);
      __syncthreads();
    }
  }

  if constexpr (OUTBF16) {
    ushort* C = (ushort*)Cv;
#pragma unroll
    for (int m = 0; m < MR; ++m)
#pragma unroll
      for (int n = 0; n < 4; ++n)
#pragma unroll
        for (int j = 0; j < 4; ++j) {
          int row = bm + wr * (MR * 16) + m * 16 + kb * 4 + j;
          int col = bn + wc * 64 + n * 16 + fr;
          C[(size_t)row * ldc + col] = f2bf(acc[m][n][j]);
        }
  } else {
    float* C = (float*)Cv;
#pragma unroll
    for (int m = 0; m < MR; ++m)
#pragma unroll
      for (int n = 0; n < 4; ++n)
#pragma unroll
        for (int j = 0; j < 4; ++j) {
          int row = bm + wr * (MR * 16) + m * 16 + kb * 4 + j;
          int col = bn + wc * 64 + n * 16 + fr;
          C[(size_t)row * ldc + col] = acc[m][n][j];
        }
  }
}

// ---------------- local attention: split K/V phases, 38.4KB LDS, 4 blocks/CU ----------------
// One block per (batch, head, 4x8x8 tile); 256 threads = 1 token each.
// ONE 64B-per-row buffer (600 rows) reused: stage K -> scores -> barrier ->
// stage V -> PV. Row = 4 x 16B quads, quad q at slot q^(row&3): worst-case
// 2-way bank alias (free, m136). 4 blocks/CU = 4 waves/SIMD latency hiding.
#define HALO 600

__global__ __launch_bounds__(256, 4) void local_attn(const ushort* __restrict__ qkv,
                                                     ushort* __restrict__ aob) {
  __shared__ __align__(16) ushort sh[HALO * 32];   // 38400 B
  const int tile = blockIdx.x;
  const int head = blockIdx.y;
  const int b    = blockIdx.z;
  const int tz = tile >> 4;
  const int ty = (tile >> 2) & 3;
  const int tx = tile & 3;
  const int t0 = tz * 4, h0 = ty * 8, w0 = tx * 8;
  const int tid = threadIdx.x;

  auto stage = [&](int ofs) {   // ofs = DMODEL (K) or 2*DMODEL (V)
#pragma unroll
    for (int k = 0; k < 10; ++k) {
      int u = tid + k * 256;       // 2400 quad-tasks
      if (u < HALO * 4) {
        int row = u >> 2;
        int q   = u & 3;
        int ht  = row / 100;
        int rem = row - ht * 100;
        int hh  = rem / 10;
        int hw  = rem - hh * 10;
        int gt = t0 - 1 + ht, gh = h0 - 1 + hh, gw = w0 - 1 + hw;
        uint4 v = {0u, 0u, 0u, 0u};
        if (gt >= 0 && gt < TOK_T && gh >= 0 && gh < TOK_H && gw >= 0 && gw < TOK_W) {
          size_t base = ((size_t)b * NTOK + (size_t)gt * 1024 + gh * 32 + gw) * D3
                        + ofs + head * DHEAD + q * 8;
          v = *(const uint4*)(qkv + base);
        }
        *(uint4*)&sh[row * 32 + ((q ^ (row & 3)) * 8)] = v;
      }
    }
  };

  // ---- stage K ----
  stage(DMODEL);

  const int tt = tid >> 6;
  const int th = (tid >> 3) & 7;
  const int tw = tid & 7;
  const int n  = (t0 + tt) * 1024 + (h0 + th) * 32 + (w0 + tw);

  // q in registers as float2 pairs (overlaps staging latency)
  const ushort* qp = qkv + ((size_t)b * NTOK + n) * D3 + head * DHEAD;
  f32x2 q2[16];
  {
    const ushort8* qs = (const ushort8*)qp;
#pragma unroll
    for (int p = 0; p < 4; ++p) {
      union { ushort8 s; uint4 u; } v; v.s = qs[p];
      q2[p * 4 + 0] = bfpair(v.u.x);
      q2[p * 4 + 1] = bfpair(v.u.y);
      q2[p * 4 + 2] = bfpair(v.u.z);
      q2[p * 4 + 3] = bfpair(v.u.w);
    }
  }
  __syncthreads();

  // ---- scores ----
  const float scale = 0.1767766952966369f;  // 1/sqrt(32)
  float s[27];
#pragma unroll
  for (int nb = 0; nb < 27; ++nb) {
    int dt = nb / 9, dh = (nb / 3) % 3, dw = nb % 3;
    int hidx = (tt + dt) * 100 + (th + dh) * 10 + (tw + dw);
    const ushort* row = &sh[hidx * 32];
    const int sw = hidx & 3;
    f32x2 a2 = {0.f, 0.f};
#pragma unroll
    for (int p = 0; p < 4; ++p) {
      union { ushort8 s; uint4 u; } kk; kk.s = *(const ushort8*)&row[(p ^ sw) * 8];
      a2 += q2[p * 4 + 0] * bfpair(kk.u.x);
      a2 += q2[p * 4 + 1] * bfpair(kk.u.y);
      a2 += q2[p * 4 + 2] * bfpair(kk.u.z);
      a2 += q2[p * 4 + 3] * bfpair(kk.u.w);
    }
    s[nb] = (a2[0] + a2[1]) * scale;
  }
  __syncthreads();   // all K reads done before V overwrites

  // ---- stage V (same buffer) ----
  stage(2 * DMODEL);

  float mx = s[0];
#pragma unroll
  for (int nb = 1; nb < 27; ++nb) mx = fmaxf(mx, s[nb]);
  __syncthreads();

  // ---- softmax + PV ----
  f32x2 o2[16] = {};
  float sum = 0.f;
#pragma unroll
  for (int nb = 0; nb < 27; ++nb) {
    int dt = nb / 9, dh = (nb / 3) % 3, dw = nb % 3;
    int hidx = (tt + dt) * 100 + (th + dh) * 10 + (tw + dw);
    const ushort* row = &sh[hidx * 32];
    const int sw = hidx & 3;
    float p = __expf(s[nb] - mx);
    sum += p;
    f32x2 p2; p2[0] = p; p2[1] = p;
#pragma unroll
    for (int c = 0; c < 4; ++c) {
      union { ushort8 s; uint4 u; } vv; vv.s = *(const ushort8*)&row[(c ^ sw) * 8];
      o2[c * 4 + 0] += p2 * bfpair(vv.u.x);
      o2[c * 4 + 1] += p2 * bfpair(vv.u.y);
      o2[c * 4 + 2] += p2 * bfpair(vv.u.z);
      o2[c * 4 + 3] += p2 * bfpair(vv.u.w);
    }
  }

  float inv = 1.f / sum;
  ushort8 os[4];
#pragma unroll
  for (int c = 0; c < 4; ++c)
#pragma unroll
    for (int e = 0; e < 8; ++e)
      os[c][e] = f2bf(o2[c * 4 + (e >> 1)][e & 1] * inv);
  ushort8* op = (ushort8*)(aob + ((size_t)b * NTOK + n) * DMODEL + head * DHEAD);
#pragma unroll
  for (int c = 0; c < 4; ++c) op[c] = os[c];
}

// ---------------- launch ----------------
extern "C" void kernel_launch(void* const* d_in, const int* in_sizes, int n_in,
                              void* d_out, int out_size, void* d_ws, size_t ws_size,
                              hipStream_t stream) {
  const float* x     = (const float*)d_in[0];
  const float* w_qkv = (const float*)d_in[1];
  const float* w_out = (const float*)d_in[2];
  float* out = (float*)d_out;

  char* ws = (char*)d_ws;
  ushort* qkvb = (ushort*)ws;                                   // 24 MB
  ushort* aob  = (ushort*)(ws + (size_t)BATCH * NTOK * D3 * 2); // 8 MB

  // GEMM1: 128x256 tiles, 1D grid 384, XCD-colocated (NBM=128, NBN=3)
  gemm_fused<128, 256, 8, 3, true, true><<<384, 512, 0, stream>>>(
      (const void*)x, w_qkv, (void*)qkvb, D3);

  // attention: 4x8x8 tiles, split K/V phases, 4 blocks/CU
  local_attn<<<dim3(32, NHEADS, BATCH), 256, 0, stream>>>(qkvb, aob);

  // GEMM2: 64x128 tiles, 1D grid 512, XCD-colocated (NBM=256, NBN=2)
  gemm_fused<64, 128, 4, 2, false, false><<<512, 256, 0, stream>>>(
      (const void*)aob, w_out, (void*)out, DMODEL);
}

// Round 14
// 161.483 us; speedup vs baseline: 1.2758x; 1.2758x over previous
//
#include <hip/hip_runtime.h>
#include <hip/hip_bf16.h>

#define TOK_T 8
#define TOK_H 32
#define TOK_W 32
#define NTOK 8192
#define BATCH 2
#define DMODEL 256
#define D3 768
#define NHEADS 8
#define DHEAD 32

using short8  = __attribute__((ext_vector_type(8))) short;
using ushort8 = __attribute__((ext_vector_type(8))) unsigned short;
using f32x4   = __attribute__((ext_vector_type(4))) float;
using f32x2   = __attribute__((ext_vector_type(2))) float;

__device__ __forceinline__ ushort f2bf(float f) {
  __hip_bfloat16 h = __float2bfloat16(f);
  return *reinterpret_cast<ushort*>(&h);
}
__device__ __forceinline__ float bf2f(ushort u) {
  union { unsigned u; float f; } v; v.u = ((unsigned)u) << 16;
  return v.f;
}
__device__ __forceinline__ f32x2 bfpair(unsigned u) {
  union { unsigned u; float f; } lo, hi;
  lo.u = u << 16;
  hi.u = u & 0xffff0000u;
  f32x2 r; r[0] = lo.f; r[1] = hi.f;
  return r;
}

// ---------------- fused-convert GEMM (exact R12 kernel) ----------------
// 1D grid, XCD-colocating remap: xcd = bm&7, id = xcd + 8*((bm>>3)*NBN + bn).
template<int TBM, int TBN, int NW, int NBN, bool AF32, bool OUTBF16>
__global__ __launch_bounds__(NW * 64, 4) void gemm_fused(const void* __restrict__ Av,
                                                         const float* __restrict__ B,
                                                         void* __restrict__ Cv,
                                                         int ldc) {
  constexpr int NCW = TBN / 64;
  constexpr int NWR = NW / NCW;
  constexpr int MR  = TBM / (NWR * 16);
  constexpr int CHA = TBM * 4;
  constexpr int CHB = TBN * 4;
  constexpr int NT  = NW * 64;
  constexpr int CPT = (CHA + CHB) / NT;
  constexpr int SA  = CHA / NT;
  constexpr int ATILE = TBM * 32;
  constexpr int BTILE = TBN * 32;

  __shared__ __align__(16) ushort sm[2][ATILE + BTILE];

  const int tid  = threadIdx.x;
  const int lane = tid & 63;
  const int wid  = tid >> 6;
  const int wr   = wid / NCW;
  const int wc   = wid % NCW;
  const int bid  = blockIdx.x;
  const int xcd  = bid & 7;
  const int kk2  = bid >> 3;
  const int bm   = ((kk2 / NBN) * 8 + xcd) * TBM;
  const int bn   = (kk2 % NBN) * TBN;
  const int fr   = lane & 15;
  const int kb   = lane >> 4;

  float4  laf[SA > 0 ? SA : 1][2];
  ushort8 lab[SA > 0 ? SA : 1];
  float4  lbf[CPT - SA][2];

  auto load = [&](int kt) {
#pragma unroll
    for (int s = 0; s < SA; ++s) {
      int cc = tid + s * NT;
      int r = cc >> 2, sl = cc & 3;
      if constexpr (AF32) {
        const float* p = (const float*)Av + (size_t)(bm + r) * 256 + kt + sl * 8;
        laf[s][0] = *(const float4*)p;
        laf[s][1] = *(const float4*)(p + 4);
      } else {
        lab[s] = *(const ushort8*)((const ushort*)Av + (size_t)(bm + r) * 256 + kt + sl * 8);
      }
    }
#pragma unroll
    for (int s = 0; s < CPT - SA; ++s) {
      int cc = tid + (s + SA) * NT - CHA;
      int r = cc >> 2, sl = cc & 3;
      const float* p = B + (size_t)(bn + r) * 256 + kt + sl * 8;
      lbf[s][0] = *(const float4*)p;
      lbf[s][1] = *(const float4*)(p + 4);
    }
  };
  auto stow = [&](int buf) {
#pragma unroll
    for (int s = 0; s < SA; ++s) {
      int cc = tid + s * NT;
      int r = cc >> 2, sl = cc & 3;
      int sck = r * 4 + (sl ^ ((r >> 1) & 3));
      ushort8 v;
      if constexpr (AF32) {
        v[0] = f2bf(laf[s][0].x); v[1] = f2bf(laf[s][0].y);
        v[2] = f2bf(laf[s][0].z); v[3] = f2bf(laf[s][0].w);
        v[4] = f2bf(laf[s][1].x); v[5] = f2bf(laf[s][1].y);
        v[6] = f2bf(laf[s][1].z); v[7] = f2bf(laf[s][1].w);
      } else v = lab[s];
      *(ushort8*)&sm[buf][sck * 8] = v;
    }
#pragma unroll
    for (int s = 0; s < CPT - SA; ++s) {
      int cc = tid + (s + SA) * NT - CHA;
      int r = cc >> 2, sl = cc & 3;
      int sck = r * 4 + (sl ^ ((r >> 1) & 3));
      ushort8 v;
      v[0] = f2bf(lbf[s][0].x); v[1] = f2bf(lbf[s][0].y);
      v[2] = f2bf(lbf[s][0].z); v[3] = f2bf(lbf[s][0].w);
      v[4] = f2bf(lbf[s][1].x); v[5] = f2bf(lbf[s][1].y);
      v[6] = f2bf(lbf[s][1].z); v[7] = f2bf(lbf[s][1].w);
      *(ushort8*)&sm[buf][ATILE + sck * 8] = v;
    }
  };

  f32x4 acc[MR][4] = {};

  load(0);
  stow(0);
  __syncthreads();

  for (int it = 0; it < 8; ++it) {
    const int cur = it & 1;
    if (it < 7) load((it + 1) * 32);

    short8 af[MR], bf8[4];
#pragma unroll
    for (int m = 0; m < MR; ++m) {
      int r  = wr * (MR * 16) + m * 16 + fr;
      int ck = r * 4 + (kb ^ ((r >> 1) & 3));
      af[m] = *(const short8*)&sm[cur][ck * 8];
    }
#pragma unroll
    for (int n = 0; n < 4; ++n) {
      int r  = wc * 64 + n * 16 + fr;
      int ck = r * 4 + (kb ^ ((r >> 1) & 3));
      bf8[n] = *(const short8*)&sm[cur][ATILE + ck * 8];
    }
#pragma unroll
    for (int m = 0; m < MR; ++m)
#pragma unroll
      for (int n = 0; n < 4; ++n)
        acc[m][n] = __builtin_amdgcn_mfma_f32_16x16x32_bf16(af[m], bf8[n], acc[m][n], 0, 0, 0);

    if (it < 7) {
      stow(cur ^ 1);
      __syncthreads();
    }
  }

  if constexpr (OUTBF16) {
    ushort* C = (ushort*)Cv;
#pragma unroll
    for (int m = 0; m < MR; ++m)
#pragma unroll
      for (int n = 0; n < 4; ++n)
#pragma unroll
        for (int j = 0; j < 4; ++j) {
          int row = bm + wr * (MR * 16) + m * 16 + kb * 4 + j;
          int col = bn + wc * 64 + n * 16 + fr;
          C[(size_t)row * ldc + col] = f2bf(acc[m][n][j]);
        }
  } else {
    float* C = (float*)Cv;
#pragma unroll
    for (int m = 0; m < MR; ++m)
#pragma unroll
      for (int n = 0; n < 4; ++n)
#pragma unroll
        for (int j = 0; j < 4; ++j) {
          int row = bm + wr * (MR * 16) + m * 16 + kb * 4 + j;
          int col = bn + wc * 64 + n * 16 + fr;
          C[(size_t)row * ldc + col] = acc[m][n][j];
        }
  }
}

// ---------------- local attention: split K/V phases, 38.4KB LDS ----------------
// launch_bounds (256, 2): VGPR cap 256 -> compiler free to use ~128 (no spill);
// hardware occupancy = min(LDS 160/38.4 = 4, VGPR 2048/128 = 16 waves = 4) = 4 blocks/CU.
// R13's (256,4) forced 64 VGPR -> 269MB scratch spills -> 190us. This is the fix.
#define HALO 600

__global__ __launch_bounds__(256, 2) void local_attn(const ushort* __restrict__ qkv,
                                                     ushort* __restrict__ aob) {
  __shared__ __align__(16) ushort sh[HALO * 32];   // 38400 B
  const int tile = blockIdx.x;
  const int head = blockIdx.y;
  const int b    = blockIdx.z;
  const int tz = tile >> 4;
  const int ty = (tile >> 2) & 3;
  const int tx = tile & 3;
  const int t0 = tz * 4, h0 = ty * 8, w0 = tx * 8;
  const int tid = threadIdx.x;

  auto stage = [&](int ofs) {   // ofs = DMODEL (K) or 2*DMODEL (V)
#pragma unroll
    for (int k = 0; k < 10; ++k) {
      int u = tid + k * 256;       // 2400 quad-tasks
      if (u < HALO * 4) {
        int row = u >> 2;
        int q   = u & 3;
        int ht  = row / 100;
        int rem = row - ht * 100;
        int hh  = rem / 10;
        int hw  = rem - hh * 10;
        int gt = t0 - 1 + ht, gh = h0 - 1 + hh, gw = w0 - 1 + hw;
        uint4 v = {0u, 0u, 0u, 0u};
        if (gt >= 0 && gt < TOK_T && gh >= 0 && gh < TOK_H && gw >= 0 && gw < TOK_W) {
          size_t base = ((size_t)b * NTOK + (size_t)gt * 1024 + gh * 32 + gw) * D3
                        + ofs + head * DHEAD + q * 8;
          v = *(const uint4*)(qkv + base);
        }
        *(uint4*)&sh[row * 32 + ((q ^ (row & 3)) * 8)] = v;
      }
    }
  };

  // ---- stage K ----
  stage(DMODEL);

  const int tt = tid >> 6;
  const int th = (tid >> 3) & 7;
  const int tw = tid & 7;
  const int n  = (t0 + tt) * 1024 + (h0 + th) * 32 + (w0 + tw);

  // q in registers as float2 pairs (overlaps staging latency)
  const ushort* qp = qkv + ((size_t)b * NTOK + n) * D3 + head * DHEAD;
  f32x2 q2[16];
  {
    const ushort8* qs = (const ushort8*)qp;
#pragma unroll
    for (int p = 0; p < 4; ++p) {
      union { ushort8 s; uint4 u; } v; v.s = qs[p];
      q2[p * 4 + 0] = bfpair(v.u.x);
      q2[p * 4 + 1] = bfpair(v.u.y);
      q2[p * 4 + 2] = bfpair(v.u.z);
      q2[p * 4 + 3] = bfpair(v.u.w);
    }
  }
  __syncthreads();

  // ---- scores ----
  const float scale = 0.1767766952966369f;  // 1/sqrt(32)
  float s[27];
#pragma unroll
  for (int nb = 0; nb < 27; ++nb) {
    int dt = nb / 9, dh = (nb / 3) % 3, dw = nb % 3;
    int hidx = (tt + dt) * 100 + (th + dh) * 10 + (tw + dw);
    const ushort* row = &sh[hidx * 32];
    const int sw = hidx & 3;
    f32x2 a2 = {0.f, 0.f};
#pragma unroll
    for (int p = 0; p < 4; ++p) {
      union { ushort8 s; uint4 u; } kk; kk.s = *(const ushort8*)&row[(p ^ sw) * 8];
      a2 += q2[p * 4 + 0] * bfpair(kk.u.x);
      a2 += q2[p * 4 + 1] * bfpair(kk.u.y);
      a2 += q2[p * 4 + 2] * bfpair(kk.u.z);
      a2 += q2[p * 4 + 3] * bfpair(kk.u.w);
    }
    s[nb] = (a2[0] + a2[1]) * scale;
  }
  __syncthreads();   // all K reads done before V overwrites

  // ---- stage V (same buffer) ----
  stage(2 * DMODEL);

  float mx = s[0];
#pragma unroll
  for (int nb = 1; nb < 27; ++nb) mx = fmaxf(mx, s[nb]);
  __syncthreads();

  // ---- softmax + PV ----
  f32x2 o2[16] = {};
  float sum = 0.f;
#pragma unroll
  for (int nb = 0; nb < 27; ++nb) {
    int dt = nb / 9, dh = (nb / 3) % 3, dw = nb % 3;
    int hidx = (tt + dt) * 100 + (th + dh) * 10 + (tw + dw);
    const ushort* row = &sh[hidx * 32];
    const int sw = hidx & 3;
    float p = __expf(s[nb] - mx);
    sum += p;
    f32x2 p2; p2[0] = p; p2[1] = p;
#pragma unroll
    for (int c = 0; c < 4; ++c) {
      union { ushort8 s; uint4 u; } vv; vv.s = *(const ushort8*)&row[(c ^ sw) * 8];
      o2[c * 4 + 0] += p2 * bfpair(vv.u.x);
      o2[c * 4 + 1] += p2 * bfpair(vv.u.y);
      o2[c * 4 + 2] += p2 * bfpair(vv.u.z);
      o2[c * 4 + 3] += p2 * bfpair(vv.u.w);
    }
  }

  float inv = 1.f / sum;
  ushort8 os[4];
#pragma unroll
  for (int c = 0; c < 4; ++c)
#pragma unroll
    for (int e = 0; e < 8; ++e)
      os[c][e] = f2bf(o2[c * 4 + (e >> 1)][e & 1] * inv);
  ushort8* op = (ushort8*)(aob + ((size_t)b * NTOK + n) * DMODEL + head * DHEAD);
#pragma unroll
  for (int c = 0; c < 4; ++c) op[c] = os[c];
}

// ---------------- launch ----------------
extern "C" void kernel_launch(void* const* d_in, const int* in_sizes, int n_in,
                              void* d_out, int out_size, void* d_ws, size_t ws_size,
                              hipStream_t stream) {
  const float* x     = (const float*)d_in[0];
  const float* w_qkv = (const float*)d_in[1];
  const float* w_out = (const float*)d_in[2];
  float* out = (float*)d_out;

  char* ws = (char*)d_ws;
  ushort* qkvb = (ushort*)ws;                                   // 24 MB
  ushort* aob  = (ushort*)(ws + (size_t)BATCH * NTOK * D3 * 2); // 8 MB

  // GEMM1: 128x256 tiles, 1D grid 384, XCD-colocated (NBM=128, NBN=3)
  gemm_fused<128, 256, 8, 3, true, true><<<384, 512, 0, stream>>>(
      (const void*)x, w_qkv, (void*)qkvb, D3);

  // attention: 4x8x8 tiles, split K/V phases
  local_attn<<<dim3(32, NHEADS, BATCH), 256, 0, stream>>>(qkvb, aob);

  // GEMM2: 64x128 tiles, 1D grid 512, XCD-colocated (NBM=256, NBN=2)
  gemm_fused<64, 128, 4, 2, false, false><<<512, 256, 0, stream>>>(
      (const void*)aob, w_out, (void*)out, DMODEL);
}

// Round 15
// 55.524 us; speedup vs baseline: 3.7103x; 2.9083x over previous
//
#include <hip/hip_runtime.h>
#include <hip/hip_bf16.h>

#define TOK_T 8
#define TOK_H 32
#define TOK_W 32
#define NTOK 8192
#define BATCH 2
#define DMODEL 256
#define D3 768
#define NHEADS 8
#define DHEAD 32

using short8  = __attribute__((ext_vector_type(8))) short;
using ushort8 = __attribute__((ext_vector_type(8))) unsigned short;
using f32x4   = __attribute__((ext_vector_type(4))) float;
using f32x2   = __attribute__((ext_vector_type(2))) float;

__device__ __forceinline__ ushort f2bf(float f) {
  __hip_bfloat16 h = __float2bfloat16(f);
  return *reinterpret_cast<ushort*>(&h);
}
__device__ __forceinline__ float bf2f(ushort u) {
  union { unsigned u; float f; } v; v.u = ((unsigned)u) << 16;
  return v.f;
}
__device__ __forceinline__ f32x2 bfpair(unsigned u) {
  union { unsigned u; float f; } lo, hi;
  lo.u = u << 16;
  hi.u = u & 0xffff0000u;
  f32x2 r; r[0] = lo.f; r[1] = hi.f;
  return r;
}

// ---------------- fused-convert GEMM (R12 kernel, verbatim) ----------------
// 1D grid, XCD-colocating remap: xcd = bm&7, id = xcd + 8*((bm>>3)*NBN + bn).
// All NBN blocks sharing an A panel land on ONE XCD -> panel fetched from HBM
// once (per-XCD L2 keeps it). NBM must be a multiple of 8.
template<int TBM, int TBN, int NW, int NBN, bool AF32, bool OUTBF16>
__global__ __launch_bounds__(NW * 64, 4) void gemm_fused(const void* __restrict__ Av,
                                                         const float* __restrict__ B,
                                                         void* __restrict__ Cv,
                                                         int ldc) {
  constexpr int NCW = TBN / 64;
  constexpr int NWR = NW / NCW;
  constexpr int MR  = TBM / (NWR * 16);
  constexpr int CHA = TBM * 4;
  constexpr int CHB = TBN * 4;
  constexpr int NT  = NW * 64;
  constexpr int CPT = (CHA + CHB) / NT;
  constexpr int SA  = CHA / NT;
  constexpr int ATILE = TBM * 32;
  constexpr int BTILE = TBN * 32;

  __shared__ __align__(16) ushort sm[2][ATILE + BTILE];

  const int tid  = threadIdx.x;
  const int lane = tid & 63;
  const int wid  = tid >> 6;
  const int wr   = wid / NCW;
  const int wc   = wid % NCW;
  const int bid  = blockIdx.x;
  const int xcd  = bid & 7;
  const int kk2  = bid >> 3;
  const int bm   = ((kk2 / NBN) * 8 + xcd) * TBM;
  const int bn   = (kk2 % NBN) * TBN;
  const int fr   = lane & 15;
  const int kb   = lane >> 4;

  float4  laf[SA > 0 ? SA : 1][2];
  ushort8 lab[SA > 0 ? SA : 1];
  float4  lbf[CPT - SA][2];

  auto load = [&](int kt) {
#pragma unroll
    for (int s = 0; s < SA; ++s) {
      int cc = tid + s * NT;
      int r = cc >> 2, sl = cc & 3;
      if constexpr (AF32) {
        const float* p = (const float*)Av + (size_t)(bm + r) * 256 + kt + sl * 8;
        laf[s][0] = *(const float4*)p;
        laf[s][1] = *(const float4*)(p + 4);
      } else {
        lab[s] = *(const ushort8*)((const ushort*)Av + (size_t)(bm + r) * 256 + kt + sl * 8);
      }
    }
#pragma unroll
    for (int s = 0; s < CPT - SA; ++s) {
      int cc = tid + (s + SA) * NT - CHA;
      int r = cc >> 2, sl = cc & 3;
      const float* p = B + (size_t)(bn + r) * 256 + kt + sl * 8;
      lbf[s][0] = *(const float4*)p;
      lbf[s][1] = *(const float4*)(p + 4);
    }
  };
  auto stow = [&](int buf) {
#pragma unroll
    for (int s = 0; s < SA; ++s) {
      int cc = tid + s * NT;
      int r = cc >> 2, sl = cc & 3;
      int sck = r * 4 + (sl ^ ((r >> 1) & 3));
      ushort8 v;
      if constexpr (AF32) {
        v[0] = f2bf(laf[s][0].x); v[1] = f2bf(laf[s][0].y);
        v[2] = f2bf(laf[s][0].z); v[3] = f2bf(laf[s][0].w);
        v[4] = f2bf(laf[s][1].x); v[5] = f2bf(laf[s][1].y);
        v[6] = f2bf(laf[s][1].z); v[7] = f2bf(laf[s][1].w);
      } else v = lab[s];
      *(ushort8*)&sm[buf][sck * 8] = v;
    }
#pragma unroll
    for (int s = 0; s < CPT - SA; ++s) {
      int cc = tid + (s + SA) * NT - CHA;
      int r = cc >> 2, sl = cc & 3;
      int sck = r * 4 + (sl ^ ((r >> 1) & 3));
      ushort8 v;
      v[0] = f2bf(lbf[s][0].x); v[1] = f2bf(lbf[s][0].y);
      v[2] = f2bf(lbf[s][0].z); v[3] = f2bf(lbf[s][0].w);
      v[4] = f2bf(lbf[s][1].x); v[5] = f2bf(lbf[s][1].y);
      v[6] = f2bf(lbf[s][1].z); v[7] = f2bf(lbf[s][1].w);
      *(ushort8*)&sm[buf][ATILE + sck * 8] = v;
    }
  };

  f32x4 acc[MR][4] = {};

  load(0);
  stow(0);
  __syncthreads();

  for (int it = 0; it < 8; ++it) {
    const int cur = it & 1;
    if (it < 7) load((it + 1) * 32);

    short8 af[MR], bf8[4];
#pragma unroll
    for (int m = 0; m < MR; ++m) {
      int r  = wr * (MR * 16) + m * 16 + fr;
      int ck = r * 4 + (kb ^ ((r >> 1) & 3));
      af[m] = *(const short8*)&sm[cur][ck * 8];
    }
#pragma unroll
    for (int n = 0; n < 4; ++n) {
      int r  = wc * 64 + n * 16 + fr;
      int ck = r * 4 + (kb ^ ((r >> 1) & 3));
      bf8[n] = *(const short8*)&sm[cur][ATILE + ck * 8];
    }
#pragma unroll
    for (int m = 0; m < MR; ++m)
#pragma unroll
      for (int n = 0; n < 4; ++n)
        acc[m][n] = __builtin_amdgcn_mfma_f32_16x16x32_bf16(af[m], bf8[n], acc[m][n], 0, 0, 0);

    if (it < 7) {
      stow(cur ^ 1);
      __syncthreads();
    }
  }

  if constexpr (OUTBF16) {
    ushort* C = (ushort*)Cv;
#pragma unroll
    for (int m = 0; m < MR; ++m)
#pragma unroll
      for (int n = 0; n < 4; ++n)
#pragma unroll
        for (int j = 0; j < 4; ++j) {
          int row = bm + wr * (MR * 16) + m * 16 + kb * 4 + j;
          int col = bn + wc * 64 + n * 16 + fr;
          C[(size_t)row * ldc + col] = f2bf(acc[m][n][j]);
        }
  } else {
    float* C = (float*)Cv;
#pragma unroll
    for (int m = 0; m < MR; ++m)
#pragma unroll
      for (int n = 0; n < 4; ++n)
#pragma unroll
        for (int j = 0; j < 4; ++j) {
          int row = bm + wr * (MR * 16) + m * 16 + kb * 4 + j;
          int col = bn + wc * 64 + n * 16 + fr;
          C[(size_t)row * ldc + col] = acc[m][n][j];
        }
  }
}

// ---------------- local attention (R12/R8 kernel, verbatim) ----------------
// One block per (batch, head, 4x8x8 tile); 256 threads = 1 token each.
// Halo 6x10x10 = 600 rows; row = 128B: 8x16B slots (K: 0..3, V: 4..7), stored
// at slot s ^ (row&7) -> b128 reads conflict-mitigated. 76.8 KB LDS, 2 blocks/CU.
// NOTE: do NOT split K/V phases with unrolled staging (R13/R14): register
// pressure from in-flight staging uint4s + live s[27] across barriers -> spills
// (WRITE_SIZE 194MB vs 8MB output).
#define HALO 600

__global__ __launch_bounds__(256, 2) void local_attn(const ushort* __restrict__ qkv,
                                                     ushort* __restrict__ aob) {
  __shared__ __align__(16) ushort sh[HALO * 64];   // 76800 B
  const int tile = blockIdx.x;
  const int head = blockIdx.y;
  const int b    = blockIdx.z;
  const int tz = tile >> 4;
  const int ty = (tile >> 2) & 3;
  const int tx = tile & 3;
  const int t0 = tz * 4, h0 = ty * 8, w0 = tx * 8;
  const int tid = threadIdx.x;

  for (int idx = tid; idx < HALO; idx += 256) {
    int ht  = idx / 100;
    int rem = idx - ht * 100;
    int hh  = rem / 10;
    int hw  = rem - hh * 10;
    int gt = t0 - 1 + ht, gh = h0 - 1 + hh, gw = w0 - 1 + hw;
    ushort* row = &sh[idx * 64];
    const int sw = idx & 7;
    if (gt >= 0 && gt < TOK_T && gh >= 0 && gh < TOK_H && gw >= 0 && gw < TOK_W) {
      size_t base = ((size_t)b * NTOK + (size_t)gt * 1024 + gh * 32 + gw) * D3;
      const ushort8* ks = (const ushort8*)(qkv + base + DMODEL + head * DHEAD);
      const ushort8* vs = (const ushort8*)(qkv + base + 2 * DMODEL + head * DHEAD);
#pragma unroll
      for (int p = 0; p < 4; ++p) *(ushort8*)&row[(p ^ sw) * 8]       = ks[p];
#pragma unroll
      for (int p = 0; p < 4; ++p) *(ushort8*)&row[((4 + p) ^ sw) * 8] = vs[p];
    } else {
      ushort8 z = (ushort8)0;
#pragma unroll
      for (int s = 0; s < 8; ++s) *(ushort8*)&row[s * 8] = z;
    }
  }

  const int tt = tid >> 6;
  const int th = (tid >> 3) & 7;
  const int tw = tid & 7;
  const int n  = (t0 + tt) * 1024 + (h0 + th) * 32 + (w0 + tw);

  const ushort* qp = qkv + ((size_t)b * NTOK + n) * D3 + head * DHEAD;
  f32x2 q2[16];
  {
    const ushort8* qs = (const ushort8*)qp;
#pragma unroll
    for (int p = 0; p < 4; ++p) {
      union { ushort8 s; uint4 u; } v; v.s = qs[p];
      q2[p * 4 + 0] = bfpair(v.u.x);
      q2[p * 4 + 1] = bfpair(v.u.y);
      q2[p * 4 + 2] = bfpair(v.u.z);
      q2[p * 4 + 3] = bfpair(v.u.w);
    }
  }
  __syncthreads();

  const float scale = 0.1767766952966369f;  // 1/sqrt(32)
  float s[27];
#pragma unroll
  for (int nb = 0; nb < 27; ++nb) {
    int dt = nb / 9, dh = (nb / 3) % 3, dw = nb % 3;
    int hidx = (tt + dt) * 100 + (th + dh) * 10 + (tw + dw);
    const ushort* row = &sh[hidx * 64];
    const int sw = hidx & 7;
    f32x2 a2 = {0.f, 0.f};
#pragma unroll
    for (int p = 0; p < 4; ++p) {
      union { ushort8 s; uint4 u; } kk; kk.s = *(const ushort8*)&row[(p ^ sw) * 8];
      a2 += q2[p * 4 + 0] * bfpair(kk.u.x);
      a2 += q2[p * 4 + 1] * bfpair(kk.u.y);
      a2 += q2[p * 4 + 2] * bfpair(kk.u.z);
      a2 += q2[p * 4 + 3] * bfpair(kk.u.w);
    }
    s[nb] = (a2[0] + a2[1]) * scale;
  }

  float mx = s[0];
#pragma unroll
  for (int nb = 1; nb < 27; ++nb) mx = fmaxf(mx, s[nb]);

  f32x2 o2[16] = {};
  float sum = 0.f;
#pragma unroll
  for (int nb = 0; nb < 27; ++nb) {
    int dt = nb / 9, dh = (nb / 3) % 3, dw = nb % 3;
    int hidx = (tt + dt) * 100 + (th + dh) * 10 + (tw + dw);
    const ushort* row = &sh[hidx * 64];
    const int sw = hidx & 7;
    float p = __expf(s[nb] - mx);
    sum += p;
    f32x2 p2; p2[0] = p; p2[1] = p;
#pragma unroll
    for (int c = 0; c < 4; ++c) {
      union { ushort8 s; uint4 u; } vv; vv.s = *(const ushort8*)&row[((4 + c) ^ sw) * 8];
      o2[c * 4 + 0] += p2 * bfpair(vv.u.x);
      o2[c * 4 + 1] += p2 * bfpair(vv.u.y);
      o2[c * 4 + 2] += p2 * bfpair(vv.u.z);
      o2[c * 4 + 3] += p2 * bfpair(vv.u.w);
    }
  }

  float inv = 1.f / sum;
  ushort8 os[4];
#pragma unroll
  for (int c = 0; c < 4; ++c)
#pragma unroll
    for (int e = 0; e < 8; ++e)
      os[c][e] = f2bf(o2[c * 4 + (e >> 1)][e & 1] * inv);
  ushort8* op = (ushort8*)(aob + ((size_t)b * NTOK + n) * DMODEL + head * DHEAD);
#pragma unroll
  for (int c = 0; c < 4; ++c) op[c] = os[c];
}

// ---------------- launch ----------------
extern "C" void kernel_launch(void* const* d_in, const int* in_sizes, int n_in,
                              void* d_out, int out_size, void* d_ws, size_t ws_size,
                              hipStream_t stream) {
  const float* x     = (const float*)d_in[0];
  const float* w_qkv = (const float*)d_in[1];
  const float* w_out = (const float*)d_in[2];
  float* out = (float*)d_out;

  char* ws = (char*)d_ws;
  ushort* qkvb = (ushort*)ws;                                   // 24 MB
  ushort* aob  = (ushort*)(ws + (size_t)BATCH * NTOK * D3 * 2); // 8 MB

  // GEMM1: 128x256 tiles, 1D grid 384, XCD-colocated (NBM=128, NBN=3)
  gemm_fused<128, 256, 8, 3, true, true><<<384, 512, 0, stream>>>(
      (const void*)x, w_qkv, (void*)qkvb, D3);

  // attention: 4x8x8 tiles, 2 blocks/CU (R12 config)
  local_attn<<<dim3(32, NHEADS, BATCH), 256, 0, stream>>>(qkvb, aob);

  // GEMM2: 64x128 tiles, 1D grid 512, XCD-colocated (NBM=256, NBN=2)
  gemm_fused<64, 128, 4, 2, false, false><<<512, 256, 0, stream>>>(
      (const void*)aob, w_out, (void*)out, DMODEL);
}